// Round 5
// baseline (6519.711 us; speedup 1.0000x reference)
//
#include <hip/hip_runtime.h>
#include <math.h>

// ---------------------------------------------------------------------------
// HybridBlock: rmsnorm -> LiquidCell scan -> PLIF scan -> sparse synapse +
// sigmoid gate (residual) -> rmsnorm -> SwiGLU-style FFN (residual).
// B=4, T=1024, D=1024, H=8192.
// ---------------------------------------------------------------------------

#define Bsz 4
#define Tsz 1024
#define Dsz 1024
#define Hsz 8192

typedef __attribute__((ext_vector_type(8))) short short8;
typedef __attribute__((ext_vector_type(4))) float floatx4_t;
typedef __attribute__((ext_vector_type(4))) unsigned int uint4v;

// ---- helpers --------------------------------------------------------------

__device__ __forceinline__ unsigned short f2bf(float f) {
  union { float f; unsigned u; } c; c.f = f;
  unsigned x = c.u;
  unsigned r = (x + 0x7FFFu + ((x >> 16) & 1u)) >> 16;   // RNE
  return (unsigned short)r;
}

__device__ __forceinline__ void gll16(const void* gsrc, void* ldst) {
  // async global->LDS, 16B per lane; LDS dest = wave-uniform base + lane*16
  __builtin_amdgcn_global_load_lds(
      (const __attribute__((address_space(1))) unsigned int*)gsrc,
      (__attribute__((address_space(3))) unsigned int*)ldst,
      16, 0, 0);
}

// ---- tiny prep kernels ----------------------------------------------------

__global__ void zero_u64_k(unsigned long long* p, int n) {
  int i = blockIdx.x * 256 + threadIdx.x;
  if (i < n) p[i] = 0ull;
}

// mask dtype sniffing: 0=int32, 1=uint8(bool), 2=float32
__global__ void detect_mask_k(const unsigned int* m, int* mode) {
  if (blockIdx.x == 0 && threadIdx.x == 0) {
    int md = 0;
    for (int i = 0; i < 256; ++i) {
      unsigned w = m[i];
      if (w == 0x3F800000u) { md = 2; break; }
      if (w > 1u) md = 1;
    }
    *mode = md;
  }
}

__global__ void cvt_bf16_k(const float* __restrict__ in,
                           unsigned short* __restrict__ out, int n4) {
  int i = blockIdx.x * 256 + threadIdx.x;
  if (i < n4) {
    float4 v = ((const float4*)in)[i];
    ushort4 o;
    o.x = f2bf(v.x); o.y = f2bf(v.y); o.z = f2bf(v.z); o.w = f2bf(v.w);
    ((ushort4*)out)[i] = o;
  }
}

__global__ void make_weff_k(const float* __restrict__ syn,
                            const void* __restrict__ mask,
                            const int* __restrict__ mode,
                            unsigned short* __restrict__ out, int n) {
  int i = blockIdx.x * 256 + threadIdx.x;
  if (i < n) {
    int md = *mode;
    bool on;
    if (md == 1)      on = ((const unsigned char*)mask)[i] != 0;
    else if (md == 2) on = ((const float*)mask)[i] != 0.f;
    else              on = ((const int*)mask)[i] != 0;
    out[i] = on ? f2bf(syn[i]) : (unsigned short)0;
  }
}

// ---- rmsnorm (one block per row of 1024) ----------------------------------

template<int BF16OUT>
__global__ __launch_bounds__(256)
void rmsnorm_k(const float* __restrict__ X, const float* __restrict__ w,
               void* __restrict__ out) {
  const long row = blockIdx.x;
  const float* x = X + row * Dsz;
  float4 v = ((const float4*)x)[threadIdx.x];
  float ss = v.x * v.x + v.y * v.y + v.z * v.z + v.w * v.w;
#pragma unroll
  for (int off = 32; off > 0; off >>= 1) ss += __shfl_down(ss, off);
  __shared__ float red[4];
  if ((threadIdx.x & 63) == 0) red[threadIdx.x >> 6] = ss;
  __syncthreads();
  float tot = red[0] + red[1] + red[2] + red[3];
  float scale = 1.0f / sqrtf(tot * (1.0f / Dsz) + 1e-6f);
  float4 wv = ((const float4*)w)[threadIdx.x];
  float o0 = v.x * scale * wv.x, o1 = v.y * scale * wv.y;
  float o2 = v.z * scale * wv.z, o3 = v.w * scale * wv.w;
  if (BF16OUT) {
    ushort4 o; o.x = f2bf(o0); o.y = f2bf(o1); o.z = f2bf(o2); o.w = f2bf(o3);
    ((ushort4*)out)[row * 256 + threadIdx.x] = o;
  } else {
    float4 o; o.x = o0; o.y = o1; o.z = o2; o.w = o3;
    ((float4*)out)[row * 256 + threadIdx.x] = o;
  }
}

// ---- f32 GEMM (u = a @ Wi^T + b) : precision-critical, VALU path ----------
// C[M,N] = A[M,K] * B[N,K]^T + bias[N].  BM=128 BN=64 BK=16, 256 thr, 8x4/thr.

__global__ __launch_bounds__(256)
void gemm_f32_bt(const float* __restrict__ A, const float* __restrict__ Bm,
                 const float* __restrict__ bias, float* __restrict__ C,
                 int M, int N, int K) {
  __shared__ float sA[16][128 + 4];
  __shared__ float sB[16][64 + 4];
  const int bm = blockIdx.x, bn = blockIdx.y;
  const int tid = threadIdx.x;
  const int tx = tid & 15, ty = tid >> 4;
  float cacc[8][4] = {};
  for (int k0 = 0; k0 < K; k0 += 16) {
#pragma unroll
    for (int i = 0; i < 2; ++i) {
      int slot = tid * 2 + i, row = slot >> 2, kq = slot & 3;
      float4 v = *(const float4*)(A + (long)(bm * 128 + row) * K + k0 + kq * 4);
      sA[kq * 4 + 0][row] = v.x; sA[kq * 4 + 1][row] = v.y;
      sA[kq * 4 + 2][row] = v.z; sA[kq * 4 + 3][row] = v.w;
    }
    {
      int row = tid >> 2, kq = tid & 3;
      float4 v = *(const float4*)(Bm + (long)(bn * 64 + row) * K + k0 + kq * 4);
      sB[kq * 4 + 0][row] = v.x; sB[kq * 4 + 1][row] = v.y;
      sB[kq * 4 + 2][row] = v.z; sB[kq * 4 + 3][row] = v.w;
    }
    __syncthreads();
#pragma unroll
    for (int kk = 0; kk < 16; ++kk) {
      float4 A0 = *(const float4*)&sA[kk][ty * 8];
      float4 A1 = *(const float4*)&sA[kk][ty * 8 + 4];
      float4 B0 = *(const float4*)&sB[kk][tx * 4];
      float av[8] = {A0.x, A0.y, A0.z, A0.w, A1.x, A1.y, A1.z, A1.w};
      float bv[4] = {B0.x, B0.y, B0.z, B0.w};
#pragma unroll
      for (int r = 0; r < 8; ++r)
#pragma unroll
        for (int c = 0; c < 4; ++c) cacc[r][c] += av[r] * bv[c];
    }
    __syncthreads();
  }
#pragma unroll
  for (int r = 0; r < 8; ++r) {
#pragma unroll
    for (int c = 0; c < 4; ++c) {
      int col = bn * 64 + tx * 4 + c;
      C[(long)(bm * 128 + ty * 8 + r) * N + col] = cacc[r][c] + bias[col];
    }
  }
}

// ---- persistent Liquid+PLIF scan, single-hop partial exchange -------------
// 128 blocks x 256 threads (4 waves). Block k of batch b owns output rows
// Rk=[32k,32k+32); wave w owns col-window W=[256w,256w+256).
// Per step t, each wave:
//   1. polls the 4 per-row partials for each col in W (tag==t-1), 16 u64/lane
//      via 8 dwordx4 sc1 loads all in flight (one LLC round trip)
//   2. combines (p0+p1)+(p2+p3)+u[col], tanh, updates its REGISTER copy of
//      h for W (hloc[4]) -- h itself is never exchanged
//   3. stages hloc to its private LDS quarter, runs the 32-row x 256-col
//      matvec (Wr slice in regs), shfl-reduces
//   4. publishes its 32 partials as (t<<32|f32) u64 agent stores
// The wave whose window contains Rk also keeps vstate and writes Sout.
// NO barriers, flags, or scalar wave. Tag ring depth 4 (t&3): publish of T
// requires (depth-2 window coverage of blocks) all waves published T-2 =>
// all consumed T-3 => all past reading T-4 -> overwrite-safe, deadlock-free.
// Exact-tag match makes stale/partial visibility harmless.

__global__ __launch_bounds__(256, 1)
void liquid_plif_k(const float* __restrict__ Wr, const float* __restrict__ U,
                   const float* __restrict__ liq_tau,
                   const float* __restrict__ plif_tau,
                   unsigned long long* __restrict__ P,     // [4][B][1024][4]
                   unsigned short* __restrict__ Sout) {    // (B,T,D) bf16
  const int blk = blockIdx.x;      // 0..127
  const int b = blk >> 5;
  const int k = blk & 31;
  const int base = k * 32;
  const int tid = threadIdx.x;
  const int l = tid & 63, w = tid >> 6;
  const int rg = tid & 7;          // 8 row-groups of 4 rows
  const int ck = tid >> 3;         // col-chunk (32 cols), in [8w, 8w+8)
  const int win = 256 * w;

  __shared__ float h_lds[1024];    // wave w touches only [win, win+256)

  // Wr slice -> registers, quad order rotated by ck (bank-conflict-free).
  float4 wr[4][8];
#pragma unroll
  for (int r = 0; r < 4; ++r) {
    const float* wrow = Wr + (long)(base + rg * 4 + r) * Dsz + ck * 32;
#pragma unroll
    for (int qq = 0; qq < 8; ++qq) {
      int q = (qq + ck) & 7;
      wr[r][qq] = *(const float4*)(wrow + q * 4);
    }
  }

  // per-lane decay constants for cols win + j*64 + l
  float dec[4], omdec[4], hloc[4];
#pragma unroll
  for (int j = 0; j < 4; ++j) {
    float tau = liq_tau[win + j * 64 + l];
    dec[j] = expf(-1.0f / tau);
    omdec[j] = 1.0f - dec[j];
    hloc[j] = 0.f;
  }

  // Sout duty: wave w* = k>>3, lanes half (k&1), hloc slot j0 = (k&7)>>1
  const int j0 = (k & 7) >> 1;
  const bool is_sout = (w == (k >> 3)) && ((l >> 5) == (k & 1));
  float vstate = 0.f;
  const float itau = 1.0f / plif_tau[0];

  for (int t = 1; t <= Tsz; ++t) {
    // U loads issued first (independent, complete under the poll wait)
    const float* up = U + ((long)b * Tsz + (t - 1)) * Dsz + win + l;
    float uval0 = up[0], uval1 = up[64], uval2 = up[128], uval3 = up[192];

    const unsigned want = (unsigned)(t - 1);
    const unsigned long long* src = P + (((long)((t - 1) & 3) * Bsz + b) << 12);
    const unsigned long long* pa0 = src + (size_t)(win + l) * 4;
    const unsigned long long* pa1 = pa0 + 64 * 4;
    const unsigned long long* pa2 = pa0 + 128 * 4;
    const unsigned long long* pa3 = pa0 + 192 * 4;
    uint4v q0a, q0b, q1a, q1b, q2a, q2b, q3a, q3b;
    for (;;) {
      asm volatile(
          "global_load_dwordx4 %0, %8, off sc1\n\t"
          "global_load_dwordx4 %1, %8, off offset:16 sc1\n\t"
          "global_load_dwordx4 %2, %9, off sc1\n\t"
          "global_load_dwordx4 %3, %9, off offset:16 sc1\n\t"
          "global_load_dwordx4 %4, %10, off sc1\n\t"
          "global_load_dwordx4 %5, %10, off offset:16 sc1\n\t"
          "global_load_dwordx4 %6, %11, off sc1\n\t"
          "global_load_dwordx4 %7, %11, off offset:16 sc1\n\t"
          "s_waitcnt vmcnt(0)"
          : "=&v"(q0a), "=&v"(q0b), "=&v"(q1a), "=&v"(q1b),
            "=&v"(q2a), "=&v"(q2b), "=&v"(q3a), "=&v"(q3b)
          : "v"(pa0), "v"(pa1), "v"(pa2), "v"(pa3)
          : "memory");
      int ok = (q0a[1] == want) & (q0a[3] == want) & (q0b[1] == want) & (q0b[3] == want) &
               (q1a[1] == want) & (q1a[3] == want) & (q1b[1] == want) & (q1b[3] == want) &
               (q2a[1] == want) & (q2a[3] == want) & (q2b[1] == want) & (q2b[3] == want) &
               (q3a[1] == want) & (q3a[3] == want) & (q3b[1] == want) & (q3b[3] == want);
      if (__all(ok)) break;
    }

    // combine partials + u, tanh, local h update
    float sum0 = (__uint_as_float(q0a[0]) + __uint_as_float(q0a[2])) +
                 (__uint_as_float(q0b[0]) + __uint_as_float(q0b[2]));
    float sum1 = (__uint_as_float(q1a[0]) + __uint_as_float(q1a[2])) +
                 (__uint_as_float(q1b[0]) + __uint_as_float(q1b[2]));
    float sum2 = (__uint_as_float(q2a[0]) + __uint_as_float(q2a[2])) +
                 (__uint_as_float(q2b[0]) + __uint_as_float(q2b[2]));
    float sum3 = (__uint_as_float(q3a[0]) + __uint_as_float(q3a[2])) +
                 (__uint_as_float(q3b[0]) + __uint_as_float(q3b[2]));
    float z0 = sum0 + uval0, z1 = sum1 + uval1, z2 = sum2 + uval2, z3 = sum3 + uval3;
    // fast tanh: 1 - 2/(e^{2z}+1)
    float f0 = 1.0f - 2.0f * __builtin_amdgcn_rcpf(__expf(2.0f * z0) + 1.0f);
    float f1 = 1.0f - 2.0f * __builtin_amdgcn_rcpf(__expf(2.0f * z1) + 1.0f);
    float f2 = 1.0f - 2.0f * __builtin_amdgcn_rcpf(__expf(2.0f * z2) + 1.0f);
    float f3 = 1.0f - 2.0f * __builtin_amdgcn_rcpf(__expf(2.0f * z3) + 1.0f);
    hloc[0] = hloc[0] * dec[0] + omdec[0] * f0;
    hloc[1] = hloc[1] * dec[1] + omdec[1] * f1;
    hloc[2] = hloc[2] * dec[2] + omdec[2] * f2;
    hloc[3] = hloc[3] * dec[3] + omdec[3] * f3;

    // PLIF + spike output (one wave, 32 lanes; static hloc index via unroll)
    if (is_sout) {
#pragma unroll
      for (int j = 0; j < 4; ++j) {
        if (j == j0) {
          vstate += (hloc[j] - vstate) * itau;
          float sp = ((vstate - 0.05f) > 0.f) ? 1.f : 0.f;
          vstate -= sp * 0.05f;
          Sout[((long)b * Tsz + (t - 1)) * Dsz + base + (l & 31)] =
              (sp > 0.f) ? (unsigned short)0x3F80 : (unsigned short)0;
        }
      }
    }

    // stage hloc to this wave's LDS quarter (same-wave ds ordering only)
    h_lds[win + l]       = hloc[0];
    h_lds[win + l + 64]  = hloc[1];
    h_lds[win + l + 128] = hloc[2];
    h_lds[win + l + 192] = hloc[3];
    asm volatile("s_waitcnt lgkmcnt(0)" ::: "memory");

    // matvec: 4 rows x 32 cols per thread, over this wave's window
    float acc0 = 0.f, acc1 = 0.f, acc2 = 0.f, acc3 = 0.f;
    const float* hch = &h_lds[ck * 32];
#pragma unroll
    for (int qq = 0; qq < 8; ++qq) {
      const int q = (qq + ck) & 7;
      float4 hv = *(const float4*)(hch + q * 4);
      acc0 += wr[0][qq].x * hv.x + wr[0][qq].y * hv.y + wr[0][qq].z * hv.z + wr[0][qq].w * hv.w;
      acc1 += wr[1][qq].x * hv.x + wr[1][qq].y * hv.y + wr[1][qq].z * hv.z + wr[1][qq].w * hv.w;
      acc2 += wr[2][qq].x * hv.x + wr[2][qq].y * hv.y + wr[2][qq].z * hv.z + wr[2][qq].w * hv.w;
      acc3 += wr[3][qq].x * hv.x + wr[3][qq].y * hv.y + wr[3][qq].z * hv.z + wr[3][qq].w * hv.w;
    }
    // reduce over the wave's 8 col-chunks (lane bits 3..5)
    acc0 += __shfl_xor(acc0, 8); acc0 += __shfl_xor(acc0, 16); acc0 += __shfl_xor(acc0, 32);
    acc1 += __shfl_xor(acc1, 8); acc1 += __shfl_xor(acc1, 16); acc1 += __shfl_xor(acc1, 32);
    acc2 += __shfl_xor(acc2, 8); acc2 += __shfl_xor(acc2, 16); acc2 += __shfl_xor(acc2, 32);
    acc3 += __shfl_xor(acc3, 8); acc3 += __shfl_xor(acc3, 16); acc3 += __shfl_xor(acc3, 32);

    // publish this wave's 32 partials (lanes 0..7 hold rg=l, rows base+4l..+4)
    if (l < 8) {
      unsigned long long* dst = P + (((long)(t & 3) * Bsz + b) << 12) +
                                ((size_t)(base + l * 4) << 2) + w;
      const unsigned long long tg = ((unsigned long long)(unsigned)t) << 32;
      __hip_atomic_store(dst,      tg | (unsigned long long)__float_as_uint(acc0),
                         __ATOMIC_RELAXED, __HIP_MEMORY_SCOPE_AGENT);
      __hip_atomic_store(dst + 4,  tg | (unsigned long long)__float_as_uint(acc1),
                         __ATOMIC_RELAXED, __HIP_MEMORY_SCOPE_AGENT);
      __hip_atomic_store(dst + 8,  tg | (unsigned long long)__float_as_uint(acc2),
                         __ATOMIC_RELAXED, __HIP_MEMORY_SCOPE_AGENT);
      __hip_atomic_store(dst + 12, tg | (unsigned long long)__float_as_uint(acc3),
                         __ATOMIC_RELAXED, __HIP_MEMORY_SCOPE_AGENT);
    }
  }
}

// ---- bf16 MFMA GEMM, C = A @ B^T, m97-style 128x128x32 tile ---------------
// A:[M,K] bf16 rm, B:[N,K] bf16 rm. NB: 1 or 2 B-matrices. EPI:
//  1: out f32 = aux0 + acc0 * sigmoid(acc1 + aux1[col])   (syn+gate residual)
//  2: out bf16 = silu(acc0) * acc1                        (FFN gate*up)
//  3: out f32 = aux0 + acc0                               (down + residual)

template<int NB, int EPI>
__global__ __launch_bounds__(256)
void gemm_bt(const unsigned short* __restrict__ A,
             const unsigned short* __restrict__ B0,
             const unsigned short* __restrict__ B1,
             const float* __restrict__ aux0, const float* __restrict__ aux1,
             void* __restrict__ outp, int M, int N, int K) {
  __shared__ unsigned short sA[128 * 32];
  __shared__ unsigned short sB[2 * 128 * 32];
  const int tid = threadIdx.x;
  const int w = tid >> 6, l = tid & 63;
  const int wm = w & 1, wn = w >> 1;
  const int bm = blockIdx.x, bn = blockIdx.y;

  floatx4_t acc[NB][4][4];
#pragma unroll
  for (int j = 0; j < NB; ++j)
#pragma unroll
    for (int m = 0; m < 4; ++m)
#pragma unroll
      for (int n = 0; n < 4; ++n) acc[j][m][n] = (floatx4_t)(0.f);

  const int rA = bm * 128 + 16 * w + (l >> 2);
  const int rB = bn * 128 + 16 * w + (l >> 2);
  const int kl = (l & 3) * 8;
  const unsigned short* gA = A + (long)rA * K + kl;
  const unsigned short* gB0 = B0 + (long)rB * K + kl;
  const unsigned short* gB1 = nullptr;
  if constexpr (NB > 1) gB1 = B1 + (long)rB * K + kl;
  unsigned short* lA = &sA[(16 * w) * 32];
  unsigned short* lB = &sB[(16 * w) * 32];

  for (int k0 = 0; k0 < K; k0 += 32) {
    gll16(gA + k0,              lA);
    gll16(gA + k0 + 64 * K,     lA + 64 * 32);
    gll16(gB0 + k0,             lB);
    gll16(gB0 + k0 + 64 * K,    lB + 64 * 32);
    if constexpr (NB > 1) {
      gll16(gB1 + k0,           lB + 128 * 32);
      gll16(gB1 + k0 + 64 * K,  lB + 192 * 32);
    }
    __syncthreads();
    short8 af[4];
#pragma unroll
    for (int m = 0; m < 4; ++m)
      af[m] = *(const short8*)&sA[(wm * 64 + m * 16 + (l & 15)) * 32 + (l >> 4) * 8];
#pragma unroll
    for (int j = 0; j < NB; ++j) {
#pragma unroll
      for (int n = 0; n < 4; ++n) {
        short8 bf = *(const short8*)&sB[j * 128 * 32 +
                        (wn * 64 + n * 16 + (l & 15)) * 32 + (l >> 4) * 8];
#pragma unroll
        for (int m = 0; m < 4; ++m)
          acc[j][m][n] = __builtin_amdgcn_mfma_f32_16x16x32_bf16(
              af[m], bf, acc[j][m][n], 0, 0, 0);
      }
    }
    __syncthreads();
  }

  const int colBase = bn * 128 + wn * 64;
  const int rowBase = bm * 128 + wm * 64;
#pragma unroll
  for (int m = 0; m < 4; ++m) {
#pragma unroll
    for (int n = 0; n < 4; ++n) {
      const int col = colBase + n * 16 + (l & 15);
#pragma unroll
      for (int j = 0; j < 4; ++j) {
        const int row = rowBase + m * 16 + (l >> 4) * 4 + j;
        const long idx = (long)row * N + col;
        float v0 = acc[0][m][n][j];
        if constexpr (EPI == 1) {
          float gsum = acc[NB - 1][m][n][j] + aux1[col];
          float sg = 1.f / (1.f + __expf(-gsum));
          ((float*)outp)[idx] = aux0[idx] + v0 * sg;
        } else if constexpr (EPI == 2) {
          float sil = v0 / (1.f + __expf(-v0));
          ((unsigned short*)outp)[idx] = f2bf(sil * acc[NB - 1][m][n][j]);
        } else {  // EPI == 3
          ((float*)outp)[idx] = aux0[idx] + v0;
        }
      }
    }
  }
}

// ---------------------------------------------------------------------------

extern "C" void kernel_launch(void* const* d_in, const int* in_sizes, int n_in,
                              void* d_out, int out_size, void* d_ws, size_t ws_size,
                              hipStream_t stream) {
  (void)in_sizes; (void)n_in; (void)out_size; (void)ws_size;

  const float* x        = (const float*)d_in[0];
  const float* ln1_w    = (const float*)d_in[1];
  const float* liq_Wi   = (const float*)d_in[2];
  const float* liq_Wr   = (const float*)d_in[3];
  const float* liq_b    = (const float*)d_in[4];
  const float* liq_tau  = (const float*)d_in[5];
  const float* plif_tau = (const float*)d_in[6];
  const float* syn_w    = (const float*)d_in[7];
  const float* gate_w   = (const float*)d_in[8];
  const float* gate_b   = (const float*)d_in[9];
  const float* ln2_w    = (const float*)d_in[10];
  const float* ffn_wg   = (const float*)d_in[11];
  const float* ffn_wu   = (const float*)d_in[12];
  const float* ffn_wd   = (const float*)d_in[13];
  const void*  mask     = d_in[14];

  char* ws = (char*)d_ws;
  const size_t MB = 1024ull * 1024ull;
  unsigned short* wg_bf   = (unsigned short*)(ws + 0 * MB);    // 16 MB
  unsigned short* wu_bf   = (unsigned short*)(ws + 16 * MB);   // 16 MB
  unsigned short* wd_bf   = (unsigned short*)(ws + 32 * MB);   // 16 MB
  unsigned short* weff_bf = (unsigned short*)(ws + 48 * MB);   // 2 MB
  unsigned short* gw_bf   = (unsigned short*)(ws + 50 * MB);   // 2 MB
  float*          x2_f    = (float*)         (ws + 52 * MB);   // 16 MB
  unsigned long long* P   = (unsigned long long*)(ws + 52 * MB); // 512 KB,
                                    // overlaps x2_f: P dead before x2 written
  unsigned short* s_bf    = (unsigned short*)(ws + 68 * MB);   // 8 MB
  unsigned short* y_bf    = (unsigned short*)(ws + 76 * MB);   // 8 MB
  unsigned short* ff_bf   = (unsigned short*)(ws + 84 * MB);   // 64 MB region
  float*          a_f     = (float*)         (ws + 84 * MB);   //   (dead before ff)
  float*          u_f     = (float*)         (ws + 100 * MB);  //   (dead before ff)
  int*            mode    = (int*)(ws + 148 * MB + 65536);
  float*          out_f   = (float*)d_out;

  const int M = Bsz * Tsz;  // 4096

  // prep: mask sniff, weight converts, partial-exchange ring init
  detect_mask_k<<<1, 64, 0, stream>>>((const unsigned int*)mask, mode);
  cvt_bf16_k<<<(Hsz * Dsz / 4) / 256, 256, 0, stream>>>(ffn_wg, wg_bf, Hsz * Dsz / 4);
  cvt_bf16_k<<<(Hsz * Dsz / 4) / 256, 256, 0, stream>>>(ffn_wu, wu_bf, Hsz * Dsz / 4);
  cvt_bf16_k<<<(Dsz * Hsz / 4) / 256, 256, 0, stream>>>(ffn_wd, wd_bf, Dsz * Hsz / 4);
  cvt_bf16_k<<<(Dsz * Dsz / 4) / 256, 256, 0, stream>>>(gate_w, gw_bf, Dsz * Dsz / 4);
  make_weff_k<<<(Dsz * Dsz) / 256, 256, 0, stream>>>(syn_w, mask, mode, weff_bf, Dsz * Dsz);
  zero_u64_k<<<256, 256, 0, stream>>>(P, 4 * Bsz * Dsz * 4);  // 64K u64

  // a = rmsnorm(x, ln1_w)  (f32)
  rmsnorm_k<0><<<M, 256, 0, stream>>>(x, ln1_w, a_f);

  // u = a @ Wi^T + liq_b  (f32, precision-critical)
  gemm_f32_bt<<<dim3(M / 128, Dsz / 64), 256, 0, stream>>>(
      a_f, liq_Wi, liq_b, u_f, M, Dsz, Dsz);

  // liquid + PLIF scan -> spikes (bf16)
  liquid_plif_k<<<128, 256, 0, stream>>>(liq_Wr, u_f, liq_tau, plif_tau, P, s_bf);

  // x2 = x + (s@weff^T) * sigmoid(s@gate_w^T + gate_b)
  gemm_bt<2, 1><<<dim3(M / 128, Dsz / 128), 256, 0, stream>>>(
      s_bf, weff_bf, gw_bf, x, gate_b, x2_f, M, Dsz, Dsz);

  // y = rmsnorm(x2, ln2_w) (bf16)
  rmsnorm_k<1><<<M, 256, 0, stream>>>(x2_f, ln2_w, y_bf);

  // ff = silu(y@wg^T) * (y@wu^T)  (bf16)
  gemm_bt<2, 2><<<dim3(M / 128, Hsz / 128), 256, 0, stream>>>(
      y_bf, wg_bf, wu_bf, nullptr, nullptr, ff_bf, M, Hsz, Dsz);

  // out = x2 + ff @ wd^T  (f32)
  gemm_bt<1, 3><<<dim3(M / 128, Dsz / 128), 256, 0, stream>>>(
      ff_bf, wd_bf, nullptr, x2_f, nullptr, out_f, M, Dsz, Hsz);
}

// Round 6
// 3002.420 us; speedup vs baseline: 2.1715x; 2.1715x over previous
//
#include <hip/hip_runtime.h>
#include <math.h>

// ---------------------------------------------------------------------------
// HybridBlock: rmsnorm -> LiquidCell scan -> PLIF scan -> sparse synapse +
// sigmoid gate (residual) -> rmsnorm -> SwiGLU-style FFN (residual).
// B=4, T=1024, D=1024, H=8192.
// ---------------------------------------------------------------------------

#define Bsz 4
#define Tsz 1024
#define Dsz 1024
#define Hsz 8192

typedef __attribute__((ext_vector_type(8))) short short8;
typedef __attribute__((ext_vector_type(4))) float floatx4_t;

// ---- helpers --------------------------------------------------------------

__device__ __forceinline__ unsigned short f2bf(float f) {
  union { float f; unsigned u; } c; c.f = f;
  unsigned x = c.u;
  unsigned r = (x + 0x7FFFu + ((x >> 16) & 1u)) >> 16;   // RNE
  return (unsigned short)r;
}

__device__ __forceinline__ void gll16(const void* gsrc, void* ldst) {
  // async global->LDS, 16B per lane; LDS dest = wave-uniform base + lane*16
  __builtin_amdgcn_global_load_lds(
      (const __attribute__((address_space(1))) unsigned int*)gsrc,
      (__attribute__((address_space(3))) unsigned int*)ldst,
      16, 0, 0);
}

// ---- tiny prep kernels ----------------------------------------------------

__global__ void zero_u64_k(unsigned long long* p, int n) {
  int i = blockIdx.x * 256 + threadIdx.x;
  if (i < n) p[i] = 0ull;
}

// mask dtype sniffing: 0=int32, 1=uint8(bool), 2=float32
__global__ void detect_mask_k(const unsigned int* m, int* mode) {
  if (blockIdx.x == 0 && threadIdx.x == 0) {
    int md = 0;
    for (int i = 0; i < 256; ++i) {
      unsigned w = m[i];
      if (w == 0x3F800000u) { md = 2; break; }
      if (w > 1u) md = 1;
    }
    *mode = md;
  }
}

__global__ void cvt_bf16_k(const float* __restrict__ in,
                           unsigned short* __restrict__ out, int n4) {
  int i = blockIdx.x * 256 + threadIdx.x;
  if (i < n4) {
    float4 v = ((const float4*)in)[i];
    ushort4 o;
    o.x = f2bf(v.x); o.y = f2bf(v.y); o.z = f2bf(v.z); o.w = f2bf(v.w);
    ((ushort4*)out)[i] = o;
  }
}

__global__ void make_weff_k(const float* __restrict__ syn,
                            const void* __restrict__ mask,
                            const int* __restrict__ mode,
                            unsigned short* __restrict__ out, int n) {
  int i = blockIdx.x * 256 + threadIdx.x;
  if (i < n) {
    int md = *mode;
    bool on;
    if (md == 1)      on = ((const unsigned char*)mask)[i] != 0;
    else if (md == 2) on = ((const float*)mask)[i] != 0.f;
    else              on = ((const int*)mask)[i] != 0;
    out[i] = on ? f2bf(syn[i]) : (unsigned short)0;
  }
}

// ---- rmsnorm (one block per row of 1024) ----------------------------------

template<int BF16OUT>
__global__ __launch_bounds__(256)
void rmsnorm_k(const float* __restrict__ X, const float* __restrict__ w,
               void* __restrict__ out) {
  const long row = blockIdx.x;
  const float* x = X + row * Dsz;
  float4 v = ((const float4*)x)[threadIdx.x];
  float ss = v.x * v.x + v.y * v.y + v.z * v.z + v.w * v.w;
#pragma unroll
  for (int off = 32; off > 0; off >>= 1) ss += __shfl_down(ss, off);
  __shared__ float red[4];
  if ((threadIdx.x & 63) == 0) red[threadIdx.x >> 6] = ss;
  __syncthreads();
  float tot = red[0] + red[1] + red[2] + red[3];
  float scale = 1.0f / sqrtf(tot * (1.0f / Dsz) + 1e-6f);
  float4 wv = ((const float4*)w)[threadIdx.x];
  float o0 = v.x * scale * wv.x, o1 = v.y * scale * wv.y;
  float o2 = v.z * scale * wv.z, o3 = v.w * scale * wv.w;
  if (BF16OUT) {
    ushort4 o; o.x = f2bf(o0); o.y = f2bf(o1); o.z = f2bf(o2); o.w = f2bf(o3);
    ((ushort4*)out)[row * 256 + threadIdx.x] = o;
  } else {
    float4 o; o.x = o0; o.y = o1; o.z = o2; o.w = o3;
    ((float4*)out)[row * 256 + threadIdx.x] = o;
  }
}

// ---- f32 GEMM (u = a @ Wi^T + b) : precision-critical, VALU path ----------
// C[M,N] = A[M,K] * B[N,K]^T + bias[N].  BM=128 BN=64 BK=16, 256 thr, 8x4/thr.

__global__ __launch_bounds__(256)
void gemm_f32_bt(const float* __restrict__ A, const float* __restrict__ Bm,
                 const float* __restrict__ bias, float* __restrict__ C,
                 int M, int N, int K) {
  __shared__ float sA[16][128 + 4];
  __shared__ float sB[16][64 + 4];
  const int bm = blockIdx.x, bn = blockIdx.y;
  const int tid = threadIdx.x;
  const int tx = tid & 15, ty = tid >> 4;
  float cacc[8][4] = {};
  for (int k0 = 0; k0 < K; k0 += 16) {
#pragma unroll
    for (int i = 0; i < 2; ++i) {
      int slot = tid * 2 + i, row = slot >> 2, kq = slot & 3;
      float4 v = *(const float4*)(A + (long)(bm * 128 + row) * K + k0 + kq * 4);
      sA[kq * 4 + 0][row] = v.x; sA[kq * 4 + 1][row] = v.y;
      sA[kq * 4 + 2][row] = v.z; sA[kq * 4 + 3][row] = v.w;
    }
    {
      int row = tid >> 2, kq = tid & 3;
      float4 v = *(const float4*)(Bm + (long)(bn * 64 + row) * K + k0 + kq * 4);
      sB[kq * 4 + 0][row] = v.x; sB[kq * 4 + 1][row] = v.y;
      sB[kq * 4 + 2][row] = v.z; sB[kq * 4 + 3][row] = v.w;
    }
    __syncthreads();
#pragma unroll
    for (int kk = 0; kk < 16; ++kk) {
      float4 A0 = *(const float4*)&sA[kk][ty * 8];
      float4 A1 = *(const float4*)&sA[kk][ty * 8 + 4];
      float4 B0 = *(const float4*)&sB[kk][tx * 4];
      float av[8] = {A0.x, A0.y, A0.z, A0.w, A1.x, A1.y, A1.z, A1.w};
      float bv[4] = {B0.x, B0.y, B0.z, B0.w};
#pragma unroll
      for (int r = 0; r < 8; ++r)
#pragma unroll
        for (int c = 0; c < 4; ++c) cacc[r][c] += av[r] * bv[c];
    }
    __syncthreads();
  }
#pragma unroll
  for (int r = 0; r < 8; ++r) {
#pragma unroll
    for (int c = 0; c < 4; ++c) {
      int col = bn * 64 + tx * 4 + c;
      C[(long)(bm * 128 + ty * 8 + r) * N + col] = cacc[r][c] + bias[col];
    }
  }
}

// ---- persistent Liquid+PLIF scan ------------------------------------------
// 128 blocks x 256 threads (4 waves). Same proven exchange as r3: tagged u64
// (step<<32|f32) agent-scope h-exchange, depth-2 parity ring, wave-aligned
// window polls, no block barrier in the loop. CHANGE vs r3: the dedicated
// scalar wave is gone. After a wave posts its flag it spins on all 4 flags
// itself, then ALL FOUR waves redundantly combine the partials and run the
// deterministic tanh/decay/PLIF update for all 32 rows in lanes 0..31
// (identical arithmetic -> identical state in every wave). Wave w publishes
// only rows [8w,8w+8) (one contiguous 64B line) and writes that slice of
// Sout. This removes the scalar-wave wake hop from the serial chain.
// Safety induction unchanged: publish of t still requires all 4 flags(t)
// = whole block consumed t-1, so the depth-2 ring overwrite is race-free.

__global__ __launch_bounds__(256)
void liquid_plif_k(const float* __restrict__ Wr, const float* __restrict__ U,
                   const float* __restrict__ liq_tau,
                   const float* __restrict__ plif_tau,
                   unsigned long long* __restrict__ Hex,   // [2][B][D]
                   unsigned short* __restrict__ Sout) {    // (B,T,D) bf16
  const int blk = blockIdx.x;          // 0..127
  const int b = blk >> 5;
  const int base = (blk & 31) * 32;
  const int tid = threadIdx.x;
  const int l = tid & 63, w = tid >> 6;
  const int rg = tid & 7;        // 8 row-groups of 4 rows
  const int ck = tid >> 3;       // col-chunk 8w..8w+7 (32 cols each)
  const int win = 256 * w;

  __shared__ float h_lds[1024];
  __shared__ __align__(16) float red[2][4][8][4];
  __shared__ int flags[2][4];

  if (tid < 8) ((int*)flags)[tid] = 0;
  __syncthreads();

  // Wr slice -> registers, quad order rotated by ck (bank-conflict-free).
  float4 wr[4][8];
#pragma unroll
  for (int r = 0; r < 4; ++r) {
    const float* wrow = Wr + (long)(base + rg * 4 + r) * Dsz + ck * 32;
#pragma unroll
    for (int qq = 0; qq < 8; ++qq) {
      int q = (qq + ck) & 7;
      wr[r][qq] = *(const float4*)(wrow + q * 4);
    }
  }

  // scalar-update constants, redundantly in lanes 0..31 of EVERY wave
  float hstate = 0.f, vstate = 0.f, dec = 0.f, omdec = 0.f, itau = 0.f;
  if (l < 32) {
    float tau = liq_tau[base + l];
    dec = expf(-1.0f / tau);
    omdec = 1.0f - dec;
    itau = 1.0f / plif_tau[0];
  }

  for (int t = 1; t <= Tsz; ++t) {
    // U load issued early; completes under the poll wait
    float uval = 0.f;
    if (l < 32)
      uval = U[((long)b * Tsz + (t - 1)) * Dsz + base + l];

    const unsigned want = (unsigned)(t - 1);
    const unsigned long long* src =
        Hex + (((long)((t - 1) & 1) * Bsz + b) << 10) + win;
    unsigned long long a0, a1, a2, a3;
    for (;;) {  // 4 batched loads in flight, one wait, wave-wide check
      a0 = __hip_atomic_load(src + l,       __ATOMIC_RELAXED, __HIP_MEMORY_SCOPE_AGENT);
      a1 = __hip_atomic_load(src + l + 64,  __ATOMIC_RELAXED, __HIP_MEMORY_SCOPE_AGENT);
      a2 = __hip_atomic_load(src + l + 128, __ATOMIC_RELAXED, __HIP_MEMORY_SCOPE_AGENT);
      a3 = __hip_atomic_load(src + l + 192, __ATOMIC_RELAXED, __HIP_MEMORY_SCOPE_AGENT);
      int ok = ((unsigned)(a0 >> 32) == want) & ((unsigned)(a1 >> 32) == want) &
               ((unsigned)(a2 >> 32) == want) & ((unsigned)(a3 >> 32) == want);
      if (__all(ok)) break;
    }
    // wave-local LDS stage (no barrier: same-wave ds ordering via lgkmcnt)
    h_lds[win + l]       = __uint_as_float((unsigned)a0);
    h_lds[win + l + 64]  = __uint_as_float((unsigned)a1);
    h_lds[win + l + 128] = __uint_as_float((unsigned)a2);
    h_lds[win + l + 192] = __uint_as_float((unsigned)a3);

    float acc0 = 0.f, acc1 = 0.f, acc2 = 0.f, acc3 = 0.f;
    const float* hch = &h_lds[ck * 32];
#pragma unroll
    for (int qq = 0; qq < 8; ++qq) {
      const int q = (qq + ck) & 7;
      float4 hv = *(const float4*)(hch + q * 4);
      acc0 += wr[0][qq].x * hv.x + wr[0][qq].y * hv.y + wr[0][qq].z * hv.z + wr[0][qq].w * hv.w;
      acc1 += wr[1][qq].x * hv.x + wr[1][qq].y * hv.y + wr[1][qq].z * hv.z + wr[1][qq].w * hv.w;
      acc2 += wr[2][qq].x * hv.x + wr[2][qq].y * hv.y + wr[2][qq].z * hv.z + wr[2][qq].w * hv.w;
      acc3 += wr[3][qq].x * hv.x + wr[3][qq].y * hv.y + wr[3][qq].z * hv.z + wr[3][qq].w * hv.w;
    }
    // reduce over the wave's 8 col-chunks (lane bits 3..5)
    acc0 += __shfl_xor(acc0, 8); acc0 += __shfl_xor(acc0, 16); acc0 += __shfl_xor(acc0, 32);
    acc1 += __shfl_xor(acc1, 8); acc1 += __shfl_xor(acc1, 16); acc1 += __shfl_xor(acc1, 32);
    acc2 += __shfl_xor(acc2, 8); acc2 += __shfl_xor(acc2, 16); acc2 += __shfl_xor(acc2, 32);
    acc3 += __shfl_xor(acc3, 8); acc3 += __shfl_xor(acc3, 16); acc3 += __shfl_xor(acc3, 32);
    const int p = t & 1;
    if ((l & 56) == 0) {
      float4 rv; rv.x = acc0; rv.y = acc1; rv.z = acc2; rv.w = acc3;
      *(float4*)&red[p][w][rg][0] = rv;
    }
    // drain this wave's LDS writes (all lanes), then signal
    asm volatile("s_waitcnt lgkmcnt(0)" ::: "memory");
    if (l == 0)
      __hip_atomic_store(&flags[p][w], t, __ATOMIC_RELEASE,
                         __HIP_MEMORY_SCOPE_WORKGROUP);

    // every wave waits for all 4 flags, then combines redundantly
    for (;;) {
      int f0 = __hip_atomic_load(&flags[p][0], __ATOMIC_ACQUIRE, __HIP_MEMORY_SCOPE_WORKGROUP);
      int f1 = __hip_atomic_load(&flags[p][1], __ATOMIC_ACQUIRE, __HIP_MEMORY_SCOPE_WORKGROUP);
      int f2 = __hip_atomic_load(&flags[p][2], __ATOMIC_ACQUIRE, __HIP_MEMORY_SCOPE_WORKGROUP);
      int f3 = __hip_atomic_load(&flags[p][3], __ATOMIC_ACQUIRE, __HIP_MEMORY_SCOPE_WORKGROUP);
      if ((f0 == t) & (f1 == t) & (f2 == t) & (f3 == t)) break;
    }
    if (l < 32) {
      const int r2 = l >> 2, jj = l & 3;
      float sum = red[p][0][r2][jj] + red[p][1][r2][jj] +
                  red[p][2][r2][jj] + red[p][3][r2][jj];
      // fast tanh: 1 - 2/(e^{2z}+1)
      float z = sum + uval;
      float ex = __expf(2.0f * z);
      float f = 1.0f - 2.0f * __builtin_amdgcn_rcpf(ex + 1.0f);
      hstate = hstate * dec + omdec * f;
      vstate += (hstate - vstate) * itau;
      float sp = ((vstate - 0.05f) > 0.f) ? 1.f : 0.f;
      vstate -= sp * 0.05f;
      if ((l >> 3) == w) {   // wave w publishes rows [8w, 8w+8) (one 64B line)
        const long pidx = (((long)p * Bsz + b) << 10) + base + l;
        unsigned long long pv =
            (((unsigned long long)(unsigned)t) << 32) |
            (unsigned long long)__float_as_uint(hstate);
        __hip_atomic_store(&Hex[pidx], pv, __ATOMIC_RELAXED,
                           __HIP_MEMORY_SCOPE_AGENT);
        Sout[((long)b * Tsz + (t - 1)) * Dsz + base + l] =
            (sp > 0.f) ? (unsigned short)0x3F80 : (unsigned short)0;
      }
    }
  }
}

// ---- bf16 MFMA GEMM, C = A @ B^T, m97-style 128x128x32 tile ---------------
// A:[M,K] bf16 rm, B:[N,K] bf16 rm. NB: 1 or 2 B-matrices. EPI:
//  1: out f32 = aux0 + acc0 * sigmoid(acc1 + aux1[col])   (syn+gate residual)
//  2: out bf16 = silu(acc0) * acc1                        (FFN gate*up)
//  3: out f32 = aux0 + acc0                               (down + residual)

template<int NB, int EPI>
__global__ __launch_bounds__(256)
void gemm_bt(const unsigned short* __restrict__ A,
             const unsigned short* __restrict__ B0,
             const unsigned short* __restrict__ B1,
             const float* __restrict__ aux0, const float* __restrict__ aux1,
             void* __restrict__ outp, int M, int N, int K) {
  __shared__ unsigned short sA[128 * 32];
  __shared__ unsigned short sB[2 * 128 * 32];
  const int tid = threadIdx.x;
  const int w = tid >> 6, l = tid & 63;
  const int wm = w & 1, wn = w >> 1;
  const int bm = blockIdx.x, bn = blockIdx.y;

  floatx4_t acc[NB][4][4];
#pragma unroll
  for (int j = 0; j < NB; ++j)
#pragma unroll
    for (int m = 0; m < 4; ++m)
#pragma unroll
      for (int n = 0; n < 4; ++n) acc[j][m][n] = (floatx4_t)(0.f);

  const int rA = bm * 128 + 16 * w + (l >> 2);
  const int rB = bn * 128 + 16 * w + (l >> 2);
  const int kl = (l & 3) * 8;
  const unsigned short* gA = A + (long)rA * K + kl;
  const unsigned short* gB0 = B0 + (long)rB * K + kl;
  const unsigned short* gB1 = nullptr;
  if constexpr (NB > 1) gB1 = B1 + (long)rB * K + kl;
  unsigned short* lA = &sA[(16 * w) * 32];
  unsigned short* lB = &sB[(16 * w) * 32];

  for (int k0 = 0; k0 < K; k0 += 32) {
    gll16(gA + k0,              lA);
    gll16(gA + k0 + 64 * K,     lA + 64 * 32);
    gll16(gB0 + k0,             lB);
    gll16(gB0 + k0 + 64 * K,    lB + 64 * 32);
    if constexpr (NB > 1) {
      gll16(gB1 + k0,           lB + 128 * 32);
      gll16(gB1 + k0 + 64 * K,  lB + 192 * 32);
    }
    __syncthreads();
    short8 af[4];
#pragma unroll
    for (int m = 0; m < 4; ++m)
      af[m] = *(const short8*)&sA[(wm * 64 + m * 16 + (l & 15)) * 32 + (l >> 4) * 8];
#pragma unroll
    for (int j = 0; j < NB; ++j) {
#pragma unroll
      for (int n = 0; n < 4; ++n) {
        short8 bf = *(const short8*)&sB[j * 128 * 32 +
                        (wn * 64 + n * 16 + (l & 15)) * 32 + (l >> 4) * 8];
#pragma unroll
        for (int m = 0; m < 4; ++m)
          acc[j][m][n] = __builtin_amdgcn_mfma_f32_16x16x32_bf16(
              af[m], bf, acc[j][m][n], 0, 0, 0);
      }
    }
    __syncthreads();
  }

  const int colBase = bn * 128 + wn * 64;
  const int rowBase = bm * 128 + wm * 64;
#pragma unroll
  for (int m = 0; m < 4; ++m) {
#pragma unroll
    for (int n = 0; n < 4; ++n) {
      const int col = colBase + n * 16 + (l & 15);
#pragma unroll
      for (int j = 0; j < 4; ++j) {
        const int row = rowBase + m * 16 + (l >> 4) * 4 + j;
        const long idx = (long)row * N + col;
        float v0 = acc[0][m][n][j];
        if constexpr (EPI == 1) {
          float gsum = acc[NB - 1][m][n][j] + aux1[col];
          float sg = 1.f / (1.f + __expf(-gsum));
          ((float*)outp)[idx] = aux0[idx] + v0 * sg;
        } else if constexpr (EPI == 2) {
          float sil = v0 / (1.f + __expf(-v0));
          ((unsigned short*)outp)[idx] = f2bf(sil * acc[NB - 1][m][n][j]);
        } else {  // EPI == 3
          ((float*)outp)[idx] = aux0[idx] + v0;
        }
      }
    }
  }
}

// ---------------------------------------------------------------------------

extern "C" void kernel_launch(void* const* d_in, const int* in_sizes, int n_in,
                              void* d_out, int out_size, void* d_ws, size_t ws_size,
                              hipStream_t stream) {
  (void)in_sizes; (void)n_in; (void)out_size; (void)ws_size;

  const float* x        = (const float*)d_in[0];
  const float* ln1_w    = (const float*)d_in[1];
  const float* liq_Wi   = (const float*)d_in[2];
  const float* liq_Wr   = (const float*)d_in[3];
  const float* liq_b    = (const float*)d_in[4];
  const float* liq_tau  = (const float*)d_in[5];
  const float* plif_tau = (const float*)d_in[6];
  const float* syn_w    = (const float*)d_in[7];
  const float* gate_w   = (const float*)d_in[8];
  const float* gate_b   = (const float*)d_in[9];
  const float* ln2_w    = (const float*)d_in[10];
  const float* ffn_wg   = (const float*)d_in[11];
  const float* ffn_wu   = (const float*)d_in[12];
  const float* ffn_wd   = (const float*)d_in[13];
  const void*  mask     = d_in[14];

  char* ws = (char*)d_ws;
  const size_t MB = 1024ull * 1024ull;
  unsigned short* wg_bf   = (unsigned short*)(ws + 0 * MB);    // 16 MB
  unsigned short* wu_bf   = (unsigned short*)(ws + 16 * MB);   // 16 MB
  unsigned short* wd_bf   = (unsigned short*)(ws + 32 * MB);   // 16 MB
  unsigned short* weff_bf = (unsigned short*)(ws + 48 * MB);   // 2 MB
  unsigned short* gw_bf   = (unsigned short*)(ws + 50 * MB);   // 2 MB
  float*          x2_f    = (float*)         (ws + 52 * MB);   // 16 MB
  unsigned short* s_bf    = (unsigned short*)(ws + 68 * MB);   // 8 MB
  unsigned short* y_bf    = (unsigned short*)(ws + 76 * MB);   // 8 MB
  unsigned short* ff_bf   = (unsigned short*)(ws + 84 * MB);   // 64 MB region
  float*          a_f     = (float*)         (ws + 84 * MB);   //   (dead before ff)
  float*          u_f     = (float*)         (ws + 100 * MB);  //   (dead before ff)
  unsigned long long* hex = (unsigned long long*)(ws + 148 * MB); // 64 KB
  int*            mode    = (int*)(ws + 148 * MB + 65536);
  float*          out_f   = (float*)d_out;

  const int M = Bsz * Tsz;  // 4096

  // prep: mask sniff, weight converts, exchange-buffer init
  detect_mask_k<<<1, 64, 0, stream>>>((const unsigned int*)mask, mode);
  cvt_bf16_k<<<(Hsz * Dsz / 4) / 256, 256, 0, stream>>>(ffn_wg, wg_bf, Hsz * Dsz / 4);
  cvt_bf16_k<<<(Hsz * Dsz / 4) / 256, 256, 0, stream>>>(ffn_wu, wu_bf, Hsz * Dsz / 4);
  cvt_bf16_k<<<(Dsz * Hsz / 4) / 256, 256, 0, stream>>>(ffn_wd, wd_bf, Dsz * Hsz / 4);
  cvt_bf16_k<<<(Dsz * Dsz / 4) / 256, 256, 0, stream>>>(gate_w, gw_bf, Dsz * Dsz / 4);
  make_weff_k<<<(Dsz * Dsz) / 256, 256, 0, stream>>>(syn_w, mask, mode, weff_bf, Dsz * Dsz);
  zero_u64_k<<<32, 256, 0, stream>>>(hex, 2 * Bsz * Dsz);

  // a = rmsnorm(x, ln1_w)  (f32)
  rmsnorm_k<0><<<M, 256, 0, stream>>>(x, ln1_w, a_f);

  // u = a @ Wi^T + liq_b  (f32, precision-critical)
  gemm_f32_bt<<<dim3(M / 128, Dsz / 64), 256, 0, stream>>>(
      a_f, liq_Wi, liq_b, u_f, M, Dsz, Dsz);

  // liquid + PLIF scan -> spikes (bf16)
  liquid_plif_k<<<128, 256, 0, stream>>>(liq_Wr, u_f, liq_tau, plif_tau, hex, s_bf);

  // x2 = x + (s@weff^T) * sigmoid(s@gate_w^T + gate_b)
  gemm_bt<2, 1><<<dim3(M / 128, Dsz / 128), 256, 0, stream>>>(
      s_bf, weff_bf, gw_bf, x, gate_b, x2_f, M, Dsz, Dsz);

  // y = rmsnorm(x2, ln2_w) (bf16)
  rmsnorm_k<1><<<M, 256, 0, stream>>>(x2_f, ln2_w, y_bf);

  // ff = silu(y@wg^T) * (y@wu^T)  (bf16)
  gemm_bt<2, 2><<<dim3(M / 128, Hsz / 128), 256, 0, stream>>>(
      y_bf, wg_bf, wu_bf, nullptr, nullptr, ff_bf, M, Hsz, Dsz);

  // out = x2 + ff @ wd^T  (f32)
  gemm_bt<1, 3><<<dim3(M / 128, Dsz / 128), 256, 0, stream>>>(
      ff_bf, wd_bf, nullptr, x2_f, nullptr, out_f, M, Dsz, Hsz);
}

// Round 7
// 2213.205 us; speedup vs baseline: 2.9458x; 1.3566x over previous
//
#include <hip/hip_runtime.h>
#include <math.h>

// ---------------------------------------------------------------------------
// HybridBlock: rmsnorm -> LiquidCell scan -> PLIF scan -> sparse synapse +
// sigmoid gate (residual) -> rmsnorm -> SwiGLU-style FFN (residual).
// B=4, T=1024, D=1024, H=8192.
// ---------------------------------------------------------------------------

#define Bsz 4
#define Tsz 1024
#define Dsz 1024
#define Hsz 8192

typedef __attribute__((ext_vector_type(8))) short short8;
typedef __attribute__((ext_vector_type(4))) float floatx4_t;

// ---- helpers --------------------------------------------------------------

__device__ __forceinline__ unsigned short f2bf(float f) {
  union { float f; unsigned u; } c; c.f = f;
  unsigned x = c.u;
  unsigned r = (x + 0x7FFFu + ((x >> 16) & 1u)) >> 16;   // RNE
  return (unsigned short)r;
}

__device__ __forceinline__ void gll16(const void* gsrc, void* ldst) {
  // async global->LDS, 16B per lane; LDS dest = wave-uniform base + lane*16
  __builtin_amdgcn_global_load_lds(
      (const __attribute__((address_space(1))) unsigned int*)gsrc,
      (__attribute__((address_space(3))) unsigned int*)ldst,
      16, 0, 0);
}

// ---- tiny prep kernels ----------------------------------------------------

__global__ void zero_u64_k(unsigned long long* p, int n) {
  int i = blockIdx.x * 256 + threadIdx.x;
  if (i < n) p[i] = 0ull;
}

// ---- rmsnorm (one block per row of 1024) ----------------------------------

template<int BF16OUT>
__global__ __launch_bounds__(256)
void rmsnorm_k(const float* __restrict__ X, const float* __restrict__ w,
               void* __restrict__ out) {
  const long row = blockIdx.x;
  const float* x = X + row * Dsz;
  float4 v = ((const float4*)x)[threadIdx.x];
  float ss = v.x * v.x + v.y * v.y + v.z * v.z + v.w * v.w;
#pragma unroll
  for (int off = 32; off > 0; off >>= 1) ss += __shfl_down(ss, off);
  __shared__ float red[4];
  if ((threadIdx.x & 63) == 0) red[threadIdx.x >> 6] = ss;
  __syncthreads();
  float tot = red[0] + red[1] + red[2] + red[3];
  float scale = 1.0f / sqrtf(tot * (1.0f / Dsz) + 1e-6f);
  float4 wv = ((const float4*)w)[threadIdx.x];
  float o0 = v.x * scale * wv.x, o1 = v.y * scale * wv.y;
  float o2 = v.z * scale * wv.z, o3 = v.w * scale * wv.w;
  if (BF16OUT) {
    ushort4 o; o.x = f2bf(o0); o.y = f2bf(o1); o.z = f2bf(o2); o.w = f2bf(o3);
    ((ushort4*)out)[row * 256 + threadIdx.x] = o;
  } else {
    float4 o; o.x = o0; o.y = o1; o.z = o2; o.w = o3;
    ((float4*)out)[row * 256 + threadIdx.x] = o;
  }
}

// ---- fused persistent kernel ----------------------------------------------
// 256 blocks x 320 threads.
// Blocks 0..127  : the r3 scan, verbatim (waves 0-3 matvec + LDS flags,
//                  wave 4 scalar combine/tanh/PLIF/publish), EXCEPT the
//                  scalar wave's U read is now a tagged-u64 poll on Utag.
// Blocks 128..255: producer blocks. Block (b,k) holds Wi rows [32k,32k+32)
//                  in VGPRs, streams t=1..1024: rmsnorm(x[b,t-1]) in-block,
//                  matvec 32x1024, publishes u+bias as (t<<32|f32) u64 to
//                  Utag (contiguous 256B per block-step). Producers run ~4x
//                  faster than the scan consumes. Afterwards they convert
//                  the FFN/gate/weff weights to bf16 (work previously done
//                  by 6 serial prep kernels).
// Tags make stale replay data harmless (values deterministic). Hex must be
// zeroed by a prior kernel (poisoned tags at t=1 would deadlock).

__global__ __launch_bounds__(320)
void liquid_plif_k(const float* __restrict__ x,
                   const float* __restrict__ ln1_w,
                   const float* __restrict__ Wi,
                   const float* __restrict__ liq_b,
                   const float* __restrict__ Wr,
                   const float* __restrict__ liq_tau,
                   const float* __restrict__ plif_tau,
                   unsigned long long* __restrict__ Hex,   // [2][B][D]
                   unsigned long long* __restrict__ Utag,  // [B][T][D]
                   unsigned short* __restrict__ Sout,      // (B,T,D) bf16
                   const float* __restrict__ ffn_wg, unsigned short* wg_bf,
                   const float* __restrict__ ffn_wu, unsigned short* wu_bf,
                   const float* __restrict__ ffn_wd, unsigned short* wd_bf,
                   const float* __restrict__ gate_w, unsigned short* gw_bf,
                   const float* __restrict__ syn_w,  const void* mask,
                   unsigned short* weff_bf) {
  const int tid = threadIdx.x;

  __shared__ float h_lds[1024];
  __shared__ __align__(16) float red[2][4][8][4];
  __shared__ int flags[2][4];
  __shared__ float red4w[4];
  __shared__ int s_mode;

  if (tid < 8) ((int*)flags)[tid] = 0;
  __syncthreads();

  if (blockIdx.x < 128) {
    // ===================== SCAN PATH (r3 verbatim + Utag poll) ============
    const int blk = blockIdx.x;
    const int b = blk >> 5;
    const int base = (blk & 31) * 32;

    if (tid < 256) {
      // ---- matvec waves ----
      const int l = tid & 63, w = tid >> 6;
      const int rg = tid & 7;
      const int ck = tid >> 3;
      const int win = 256 * w;

      float4 wr[4][8];
#pragma unroll
      for (int r = 0; r < 4; ++r) {
        const float* wrow = Wr + (long)(base + rg * 4 + r) * Dsz + ck * 32;
#pragma unroll
        for (int qq = 0; qq < 8; ++qq) {
          int q = (qq + ck) & 7;
          wr[r][qq] = *(const float4*)(wrow + q * 4);
        }
      }

      for (int t = 1; t <= Tsz; ++t) {
        const unsigned want = (unsigned)(t - 1);
        const unsigned long long* src =
            Hex + (((long)((t - 1) & 1) * Bsz + b) << 10) + win;
        unsigned long long a0, a1, a2, a3;
        for (;;) {
          a0 = __hip_atomic_load(src + l,       __ATOMIC_RELAXED, __HIP_MEMORY_SCOPE_AGENT);
          a1 = __hip_atomic_load(src + l + 64,  __ATOMIC_RELAXED, __HIP_MEMORY_SCOPE_AGENT);
          a2 = __hip_atomic_load(src + l + 128, __ATOMIC_RELAXED, __HIP_MEMORY_SCOPE_AGENT);
          a3 = __hip_atomic_load(src + l + 192, __ATOMIC_RELAXED, __HIP_MEMORY_SCOPE_AGENT);
          int ok = ((unsigned)(a0 >> 32) == want) & ((unsigned)(a1 >> 32) == want) &
                   ((unsigned)(a2 >> 32) == want) & ((unsigned)(a3 >> 32) == want);
          if (__all(ok)) break;
        }
        h_lds[win + l]       = __uint_as_float((unsigned)a0);
        h_lds[win + l + 64]  = __uint_as_float((unsigned)a1);
        h_lds[win + l + 128] = __uint_as_float((unsigned)a2);
        h_lds[win + l + 192] = __uint_as_float((unsigned)a3);

        float acc0 = 0.f, acc1 = 0.f, acc2 = 0.f, acc3 = 0.f;
        const float* hch = &h_lds[ck * 32];
#pragma unroll
        for (int qq = 0; qq < 8; ++qq) {
          const int q = (qq + ck) & 7;
          float4 hv = *(const float4*)(hch + q * 4);
          acc0 += wr[0][qq].x * hv.x + wr[0][qq].y * hv.y + wr[0][qq].z * hv.z + wr[0][qq].w * hv.w;
          acc1 += wr[1][qq].x * hv.x + wr[1][qq].y * hv.y + wr[1][qq].z * hv.z + wr[1][qq].w * hv.w;
          acc2 += wr[2][qq].x * hv.x + wr[2][qq].y * hv.y + wr[2][qq].z * hv.z + wr[2][qq].w * hv.w;
          acc3 += wr[3][qq].x * hv.x + wr[3][qq].y * hv.y + wr[3][qq].z * hv.z + wr[3][qq].w * hv.w;
        }
        acc0 += __shfl_xor(acc0, 8); acc0 += __shfl_xor(acc0, 16); acc0 += __shfl_xor(acc0, 32);
        acc1 += __shfl_xor(acc1, 8); acc1 += __shfl_xor(acc1, 16); acc1 += __shfl_xor(acc1, 32);
        acc2 += __shfl_xor(acc2, 8); acc2 += __shfl_xor(acc2, 16); acc2 += __shfl_xor(acc2, 32);
        acc3 += __shfl_xor(acc3, 8); acc3 += __shfl_xor(acc3, 16); acc3 += __shfl_xor(acc3, 32);
        if ((l & 56) == 0) {
          float4 rv; rv.x = acc0; rv.y = acc1; rv.z = acc2; rv.w = acc3;
          *(float4*)&red[t & 1][w][rg][0] = rv;
        }
        asm volatile("s_waitcnt lgkmcnt(0)" ::: "memory");
        if (l == 0)
          __hip_atomic_store(&flags[t & 1][w], t, __ATOMIC_RELEASE,
                             __HIP_MEMORY_SCOPE_WORKGROUP);
      }
    } else {
      // ---- scalar wave ----
      const int r = tid - 256;  // active lanes r<32
      float hstate = 0.f, vstate = 0.f, dec = 0.f, omdec = 0.f, itau = 0.f;
      if (r < 32) {
        float tau = liq_tau[base + r];
        dec = expf(-1.0f / tau);
        omdec = 1.0f - dec;
        itau = 1.0f / plif_tau[0];
      }
      for (int t = 1; t <= Tsz; ++t) {
        float uval = 0.f;
        if (r < 32) {   // tagged poll on producer output (usually ready)
          const unsigned long long* up =
              Utag + ((long)b * Tsz + (t - 1)) * Dsz + base + r;
          unsigned long long uv;
          do {
            uv = __hip_atomic_load(up, __ATOMIC_RELAXED, __HIP_MEMORY_SCOPE_AGENT);
          } while ((unsigned)(uv >> 32) != (unsigned)t);
          uval = __uint_as_float((unsigned)uv);
        }
        const int p = t & 1;
        for (;;) {
          int f0 = __hip_atomic_load(&flags[p][0], __ATOMIC_ACQUIRE, __HIP_MEMORY_SCOPE_WORKGROUP);
          int f1 = __hip_atomic_load(&flags[p][1], __ATOMIC_ACQUIRE, __HIP_MEMORY_SCOPE_WORKGROUP);
          int f2 = __hip_atomic_load(&flags[p][2], __ATOMIC_ACQUIRE, __HIP_MEMORY_SCOPE_WORKGROUP);
          int f3 = __hip_atomic_load(&flags[p][3], __ATOMIC_ACQUIRE, __HIP_MEMORY_SCOPE_WORKGROUP);
          if ((f0 == t) & (f1 == t) & (f2 == t) & (f3 == t)) break;
        }
        if (r < 32) {
          const int r2 = r >> 2, jj = r & 3;
          float sum = red[p][0][r2][jj] + red[p][1][r2][jj] +
                      red[p][2][r2][jj] + red[p][3][r2][jj];
          float z = sum + uval;
          float ex = __expf(2.0f * z);
          float f = 1.0f - 2.0f * __builtin_amdgcn_rcpf(ex + 1.0f);
          hstate = hstate * dec + omdec * f;
          vstate += (hstate - vstate) * itau;
          float sp = ((vstate - 0.05f) > 0.f) ? 1.f : 0.f;
          vstate -= sp * 0.05f;
          const long pidx = (((long)p * Bsz + b) << 10) + base + r;
          unsigned long long pv =
              (((unsigned long long)(unsigned)t) << 32) |
              (unsigned long long)__float_as_uint(hstate);
          __hip_atomic_store(&Hex[pidx], pv, __ATOMIC_RELAXED,
                             __HIP_MEMORY_SCOPE_AGENT);
          Sout[((long)b * Tsz + (t - 1)) * Dsz + base + r] =
              (sp > 0.f) ? (unsigned short)0x3F80 : (unsigned short)0;
        }
      }
    }
  } else {
    // ===================== PRODUCER PATH ==================================
    const int blk2 = blockIdx.x - 128;   // 0..127
    const int b = blk2 >> 5;
    const int base = (blk2 & 31) * 32;

    // Wi slice -> registers (same rotated layout as scan's Wr)
    const int l = tid & 63, w = tid >> 6;
    const int rg = tid & 7;
    const int ck = tid >> 3;
    float4 wi[4][8];
    if (tid < 256) {
#pragma unroll
      for (int r = 0; r < 4; ++r) {
        const float* wrow = Wi + (long)(base + rg * 4 + r) * Dsz + ck * 32;
#pragma unroll
        for (int qq = 0; qq < 8; ++qq) {
          int q = (qq + ck) & 7;
          wi[r][qq] = *(const float4*)(wrow + q * 4);
        }
      }
    }
    float4 w4 = (tid < 256) ? ((const float4*)ln1_w)[tid] : float4{0, 0, 0, 0};
    float lb = 0.f;
    if (tid >= 256 && (tid - 256) < 32) lb = liq_b[base + (tid - 256)];

    for (int t = 1; t <= Tsz; ++t) {
      // rmsnorm of x[b,t-1] in-block
      float4 xv = {0, 0, 0, 0};
      if (tid < 256) {
        xv = ((const float4*)(x + ((long)b * Tsz + (t - 1)) * Dsz))[tid];
        float ss = xv.x * xv.x + xv.y * xv.y + xv.z * xv.z + xv.w * xv.w;
#pragma unroll
        for (int off = 32; off > 0; off >>= 1) ss += __shfl_down(ss, off);
        if (l == 0) red4w[w] = ss;
      }
      __syncthreads();
      if (tid < 256) {
        float tot = red4w[0] + red4w[1] + red4w[2] + red4w[3];
        float scale = 1.0f / sqrtf(tot * (1.0f / Dsz) + 1e-6f);
        float4 av;
        av.x = xv.x * scale * w4.x; av.y = xv.y * scale * w4.y;
        av.z = xv.z * scale * w4.z; av.w = xv.w * scale * w4.w;
        ((float4*)h_lds)[tid] = av;
      }
      __syncthreads();
      if (tid < 256) {
        float acc0 = 0.f, acc1 = 0.f, acc2 = 0.f, acc3 = 0.f;
        const float* hch = &h_lds[ck * 32];
#pragma unroll
        for (int qq = 0; qq < 8; ++qq) {
          const int q = (qq + ck) & 7;
          float4 hv = *(const float4*)(hch + q * 4);
          acc0 += wi[0][qq].x * hv.x + wi[0][qq].y * hv.y + wi[0][qq].z * hv.z + wi[0][qq].w * hv.w;
          acc1 += wi[1][qq].x * hv.x + wi[1][qq].y * hv.y + wi[1][qq].z * hv.z + wi[1][qq].w * hv.w;
          acc2 += wi[2][qq].x * hv.x + wi[2][qq].y * hv.y + wi[2][qq].z * hv.z + wi[2][qq].w * hv.w;
          acc3 += wi[3][qq].x * hv.x + wi[3][qq].y * hv.y + wi[3][qq].z * hv.z + wi[3][qq].w * hv.w;
        }
        acc0 += __shfl_xor(acc0, 8); acc0 += __shfl_xor(acc0, 16); acc0 += __shfl_xor(acc0, 32);
        acc1 += __shfl_xor(acc1, 8); acc1 += __shfl_xor(acc1, 16); acc1 += __shfl_xor(acc1, 32);
        acc2 += __shfl_xor(acc2, 8); acc2 += __shfl_xor(acc2, 16); acc2 += __shfl_xor(acc2, 32);
        acc3 += __shfl_xor(acc3, 8); acc3 += __shfl_xor(acc3, 16); acc3 += __shfl_xor(acc3, 32);
        if ((l & 56) == 0) {
          float4 rv; rv.x = acc0; rv.y = acc1; rv.z = acc2; rv.w = acc3;
          *(float4*)&red[0][w][rg][0] = rv;
        }
      }
      __syncthreads();
      if (tid >= 256) {
        const int r = tid - 256;
        if (r < 32) {
          const int r2 = r >> 2, jj = r & 3;
          float sum = red[0][0][r2][jj] + red[0][1][r2][jj] +
                      red[0][2][r2][jj] + red[0][3][r2][jj] + lb;
          unsigned long long pv =
              (((unsigned long long)(unsigned)t) << 32) |
              (unsigned long long)__float_as_uint(sum);
          __hip_atomic_store(&Utag[((long)b * Tsz + (t - 1)) * Dsz + base + r],
                             pv, __ATOMIC_RELAXED, __HIP_MEMORY_SCOPE_AGENT);
        }
      }
      __syncthreads();
    }

    // ---- tail: weight conversions (previously 6 serial prep kernels) ----
    if (tid == 0) {
      int md = 0;
      const unsigned* m = (const unsigned*)mask;
      for (int i = 0; i < 256; ++i) {
        unsigned wd = m[i];
        if (wd == 0x3F800000u) { md = 2; break; }
        if (wd > 1u) md = 1;
      }
      s_mode = md;
    }
    __syncthreads();
    const int md = s_mode;
    const long gtid = (long)blk2 * 320 + tid;
    const long gstr = 128 * 320;
    const int n4big = Hsz * Dsz / 4;      // 2,097,152 float4s
    for (long i = gtid; i < n4big; i += gstr) {
      float4 v = ((const float4*)ffn_wg)[i];
      ushort4 o; o.x = f2bf(v.x); o.y = f2bf(v.y); o.z = f2bf(v.z); o.w = f2bf(v.w);
      ((ushort4*)wg_bf)[i] = o;
      v = ((const float4*)ffn_wu)[i];
      o.x = f2bf(v.x); o.y = f2bf(v.y); o.z = f2bf(v.z); o.w = f2bf(v.w);
      ((ushort4*)wu_bf)[i] = o;
      v = ((const float4*)ffn_wd)[i];
      o.x = f2bf(v.x); o.y = f2bf(v.y); o.z = f2bf(v.z); o.w = f2bf(v.w);
      ((ushort4*)wd_bf)[i] = o;
    }
    const int n4g = Dsz * Dsz / 4;
    for (long i = gtid; i < n4g; i += gstr) {
      float4 v = ((const float4*)gate_w)[i];
      ushort4 o; o.x = f2bf(v.x); o.y = f2bf(v.y); o.z = f2bf(v.z); o.w = f2bf(v.w);
      ((ushort4*)gw_bf)[i] = o;
    }
    const int nw = Dsz * Dsz;
    for (long i = gtid; i < nw; i += gstr) {
      bool on;
      if (md == 1)      on = ((const unsigned char*)mask)[i] != 0;
      else if (md == 2) on = ((const float*)mask)[i] != 0.f;
      else              on = ((const int*)mask)[i] != 0;
      weff_bf[i] = on ? f2bf(syn_w[i]) : (unsigned short)0;
    }
  }
}

// ---- bf16 MFMA GEMM, C = A @ B^T, m97-style 128x128x32 tile ---------------
// A:[M,K] bf16 rm, B:[N,K] bf16 rm. NB: 1 or 2 B-matrices. EPI:
//  1: out f32 = aux0 + acc0 * sigmoid(acc1 + aux1[col])   (syn+gate residual)
//  2: out bf16 = silu(acc0) * acc1                        (FFN gate*up)
//  3: out f32 = aux0 + acc0                               (down + residual)

template<int NB, int EPI>
__global__ __launch_bounds__(256)
void gemm_bt(const unsigned short* __restrict__ A,
             const unsigned short* __restrict__ B0,
             const unsigned short* __restrict__ B1,
             const float* __restrict__ aux0, const float* __restrict__ aux1,
             void* __restrict__ outp, int M, int N, int K) {
  __shared__ unsigned short sA[128 * 32];
  __shared__ unsigned short sB[2 * 128 * 32];
  const int tid = threadIdx.x;
  const int w = tid >> 6, l = tid & 63;
  const int wm = w & 1, wn = w >> 1;
  const int bm = blockIdx.x, bn = blockIdx.y;

  floatx4_t acc[NB][4][4];
#pragma unroll
  for (int j = 0; j < NB; ++j)
#pragma unroll
    for (int m = 0; m < 4; ++m)
#pragma unroll
      for (int n = 0; n < 4; ++n) acc[j][m][n] = (floatx4_t)(0.f);

  const int rA = bm * 128 + 16 * w + (l >> 2);
  const int rB = bn * 128 + 16 * w + (l >> 2);
  const int kl = (l & 3) * 8;
  const unsigned short* gA = A + (long)rA * K + kl;
  const unsigned short* gB0 = B0 + (long)rB * K + kl;
  const unsigned short* gB1 = nullptr;
  if constexpr (NB > 1) gB1 = B1 + (long)rB * K + kl;
  unsigned short* lA = &sA[(16 * w) * 32];
  unsigned short* lB = &sB[(16 * w) * 32];

  for (int k0 = 0; k0 < K; k0 += 32) {
    gll16(gA + k0,              lA);
    gll16(gA + k0 + 64 * K,     lA + 64 * 32);
    gll16(gB0 + k0,             lB);
    gll16(gB0 + k0 + 64 * K,    lB + 64 * 32);
    if constexpr (NB > 1) {
      gll16(gB1 + k0,           lB + 128 * 32);
      gll16(gB1 + k0 + 64 * K,  lB + 192 * 32);
    }
    __syncthreads();
    short8 af[4];
#pragma unroll
    for (int m = 0; m < 4; ++m)
      af[m] = *(const short8*)&sA[(wm * 64 + m * 16 + (l & 15)) * 32 + (l >> 4) * 8];
#pragma unroll
    for (int j = 0; j < NB; ++j) {
#pragma unroll
      for (int n = 0; n < 4; ++n) {
        short8 bf = *(const short8*)&sB[j * 128 * 32 +
                        (wn * 64 + n * 16 + (l & 15)) * 32 + (l >> 4) * 8];
#pragma unroll
        for (int m = 0; m < 4; ++m)
          acc[j][m][n] = __builtin_amdgcn_mfma_f32_16x16x32_bf16(
              af[m], bf, acc[j][m][n], 0, 0, 0);
      }
    }
    __syncthreads();
  }

  const int colBase = bn * 128 + wn * 64;
  const int rowBase = bm * 128 + wm * 64;
#pragma unroll
  for (int m = 0; m < 4; ++m) {
#pragma unroll
    for (int n = 0; n < 4; ++n) {
      const int col = colBase + n * 16 + (l & 15);
#pragma unroll
      for (int j = 0; j < 4; ++j) {
        const int row = rowBase + m * 16 + (l >> 4) * 4 + j;
        const long idx = (long)row * N + col;
        float v0 = acc[0][m][n][j];
        if constexpr (EPI == 1) {
          float gsum = acc[NB - 1][m][n][j] + aux1[col];
          float sg = 1.f / (1.f + __expf(-gsum));
          ((float*)outp)[idx] = aux0[idx] + v0 * sg;
        } else if constexpr (EPI == 2) {
          float sil = v0 / (1.f + __expf(-v0));
          ((unsigned short*)outp)[idx] = f2bf(sil * acc[NB - 1][m][n][j]);
        } else {  // EPI == 3
          ((float*)outp)[idx] = aux0[idx] + v0;
        }
      }
    }
  }
}

// ---------------------------------------------------------------------------

extern "C" void kernel_launch(void* const* d_in, const int* in_sizes, int n_in,
                              void* d_out, int out_size, void* d_ws, size_t ws_size,
                              hipStream_t stream) {
  (void)in_sizes; (void)n_in; (void)out_size; (void)ws_size;

  const float* x        = (const float*)d_in[0];
  const float* ln1_w    = (const float*)d_in[1];
  const float* liq_Wi   = (const float*)d_in[2];
  const float* liq_Wr   = (const float*)d_in[3];
  const float* liq_b    = (const float*)d_in[4];
  const float* liq_tau  = (const float*)d_in[5];
  const float* plif_tau = (const float*)d_in[6];
  const float* syn_w    = (const float*)d_in[7];
  const float* gate_w   = (const float*)d_in[8];
  const float* gate_b   = (const float*)d_in[9];
  const float* ln2_w    = (const float*)d_in[10];
  const float* ffn_wg   = (const float*)d_in[11];
  const float* ffn_wu   = (const float*)d_in[12];
  const float* ffn_wd   = (const float*)d_in[13];
  const void*  mask     = d_in[14];

  char* ws = (char*)d_ws;
  const size_t MB = 1024ull * 1024ull;
  unsigned short* wg_bf   = (unsigned short*)(ws + 0 * MB);    // 16 MB
  unsigned short* wu_bf   = (unsigned short*)(ws + 16 * MB);   // 16 MB
  unsigned short* wd_bf   = (unsigned short*)(ws + 32 * MB);   // 16 MB
  unsigned short* weff_bf = (unsigned short*)(ws + 48 * MB);   // 2 MB
  unsigned short* gw_bf   = (unsigned short*)(ws + 50 * MB);   // 2 MB
  float*          x2_f    = (float*)         (ws + 52 * MB);   // 16 MB
  unsigned short* s_bf    = (unsigned short*)(ws + 68 * MB);   // 8 MB
  unsigned short* y_bf    = (unsigned short*)(ws + 76 * MB);   // 8 MB
  unsigned short* ff_bf   = (unsigned short*)(ws + 84 * MB);   // 64 MB (84-148)
  unsigned long long* Utag= (unsigned long long*)(ws + 84 * MB); // 32 MB,
                                    // overlaps ff_bf: Utag dead before FFN
  unsigned long long* hex = (unsigned long long*)(ws + 148 * MB); // 64 KB
  float*          out_f   = (float*)d_out;

  const int M = Bsz * Tsz;  // 4096

  // Hex ring MUST be zeroed before the scan (poisoned tags would deadlock)
  zero_u64_k<<<32, 256, 0, stream>>>(hex, 2 * Bsz * Dsz);

  // fused: scan (blocks 0-127) + u-producers & weight converts (128-255)
  liquid_plif_k<<<256, 320, 0, stream>>>(
      x, ln1_w, liq_Wi, liq_b, liq_Wr, liq_tau, plif_tau, hex, Utag, s_bf,
      ffn_wg, wg_bf, ffn_wu, wu_bf, ffn_wd, wd_bf, gate_w, gw_bf,
      syn_w, mask, weff_bf);

  // x2 = x + (s@weff^T) * sigmoid(s@gate_w^T + gate_b)
  gemm_bt<2, 1><<<dim3(M / 128, Dsz / 128), 256, 0, stream>>>(
      s_bf, weff_bf, gw_bf, x, gate_b, x2_f, M, Dsz, Dsz);

  // y = rmsnorm(x2, ln2_w) (bf16)
  rmsnorm_k<1><<<M, 256, 0, stream>>>(x2_f, ln2_w, y_bf);

  // ff = silu(y@wg^T) * (y@wu^T)  (bf16)
  gemm_bt<2, 2><<<dim3(M / 128, Hsz / 128), 256, 0, stream>>>(
      y_bf, wg_bf, wu_bf, nullptr, nullptr, ff_bf, M, Hsz, Dsz);

  // out = x2 + ff @ wd^T  (f32)
  gemm_bt<1, 3><<<dim3(M / 128, Dsz / 128), 256, 0, stream>>>(
      ff_bf, wd_bf, nullptr, x2_f, nullptr, out_f, M, Dsz, Hsz);
}